// Round 2
// baseline (277.498 us; speedup 1.0000x reference)
//
#include <hip/hip_runtime.h>

#define N_SAMP 1024
#define XC_DIM 512
#define YC_DIM 256
#define HID_DIM 512

// ---------------------------------------------------------------------------
// K1: fused spatial pooling — TLP-structured (copy-bench shape).
// R1 post-mortem: the compiler refuses to keep >4-5 float4 loads live per
// thread (VGPR squeezed to 36 despite sched_barrier), so per-wave ILP is
// capped. Instead: 2 loads/thread, 32 outputs/block, 24576 blocks (96/CU,
// 8 resident) -> latency hidden by wave count, not register count.
// Per-CU in-flight target: 32 waves x 2KB = 64KB >> 22KB Little's-law need.
// ---------------------------------------------------------------------------
__global__ __launch_bounds__(256) void pool_kernel(
    const float* __restrict__ x, const float* __restrict__ y,
    float* __restrict__ x_vec, float* __restrict__ y_vec) {
  __shared__ float s[16 * 33];  // [k][o] k=0..15, o=0..31 (pad 33)
  const int t = threadIdx.x;
  const long blk = blockIdx.x;
  const float4* src;
  float* dst;
  long obase;
  if (blk < 16384) {           // x: 524288 outputs / 32 = 16384 blocks
    src = (const float4*)x; dst = x_vec; obase = blk * 32;
  } else {                     // y: 262144 outputs / 32 = 8192 blocks
    src = (const float4*)y; dst = y_vec; obase = (blk - 16384) * 32;
  }
  const float4* p = src + obase * 16;  // 512 float4 per block

  // Two independent coalesced loads per thread.
  float4 v0 = p[t];
  float4 v1 = p[t + 256];
  float h0 = (v0.x + v0.y) + (v0.z + v0.w);
  float h1 = (v1.x + v1.y) + (v1.z + v1.w);

  // f = t      -> output o = t>>4 (0..15),  k = t&15
  // f = t+256  -> output o = 16+(t>>4),     k = t&15
  s[(t & 15) * 33 + (t >> 4)] = h0;
  s[(t & 15) * 33 + 16 + (t >> 4)] = h1;
  __syncthreads();

  // 8 lanes per output: lane r sums k = 2r, 2r+1, then 3-step shuffle.
  const int o = t >> 3;        // 0..31
  const int r = t & 7;
  float dp = s[(2 * r) * 33 + o] + s[(2 * r + 1) * 33 + o];
#pragma unroll
  for (int off = 1; off < 8; off <<= 1) dp += __shfl_xor(dp, off);
  if (r == 0) dst[obase + o] = dp * (1.0f / 64.0f);
}

// ---------------------------------------------------------------------------
// K2: Hp[s] = x_vec @ W1[k-chunk s]. 64x64 tile, 4x4/thread, BK=16,
// splitK=4 (chunk 128 = 8 iters) -> grid (8,16,4) = 512 blocks = 2/CU.
// ---------------------------------------------------------------------------
#define TBK 16

__global__ __launch_bounds__(256) void gemm1_kernel(
    const float* __restrict__ A, const float* __restrict__ B,
    float* __restrict__ Hp) {
  const int K = 512, Nn = 512;
  __shared__ float As[TBK][68];
  __shared__ float Bs[TBK][68];
  const int t = threadIdx.x;
  const int bn = blockIdx.x * 64;
  const int bm = blockIdx.y * 64;
  const int ks = blockIdx.z;          // 0..3, K-chunk of 128

  const int arow = t >> 2, acol = (t & 3) * 4;
  const int brow = t >> 4, bcol = (t & 15) * 4;
  const int row0 = (t >> 4) * 4, col0 = (t & 15) * 4;

  float acc[4][4] = {};
  const int k0 = ks * 128;

  float4 av = *(const float4*)&A[(bm + arow) * K + k0 + acol];
  float4 bv = *(const float4*)&B[(k0 + brow) * Nn + bn + bcol];

  for (int it = 0; it < 8; ++it) {
    __syncthreads();
    As[acol + 0][arow] = av.x;
    As[acol + 1][arow] = av.y;
    As[acol + 2][arow] = av.z;
    As[acol + 3][arow] = av.w;
    *(float4*)&Bs[brow][bcol] = bv;
    __syncthreads();
    if (it < 7) {
      const int k1 = k0 + (it + 1) * TBK;
      av = *(const float4*)&A[(bm + arow) * K + k1 + acol];
      bv = *(const float4*)&B[(k1 + brow) * Nn + bn + bcol];
    }
#pragma unroll
    for (int kk = 0; kk < TBK; ++kk) {
      float4 a = *(const float4*)&As[kk][row0];
      float4 b = *(const float4*)&Bs[kk][col0];
      acc[0][0] += a.x * b.x; acc[0][1] += a.x * b.y; acc[0][2] += a.x * b.z; acc[0][3] += a.x * b.w;
      acc[1][0] += a.y * b.x; acc[1][1] += a.y * b.y; acc[1][2] += a.y * b.z; acc[1][3] += a.y * b.w;
      acc[2][0] += a.z * b.x; acc[2][1] += a.z * b.y; acc[2][2] += a.z * b.z; acc[2][3] += a.z * b.w;
      acc[3][0] += a.w * b.x; acc[3][1] += a.w * b.y; acc[3][2] += a.w * b.z; acc[3][3] += a.w * b.w;
    }
  }

  float* H = Hp + (long)ks * (N_SAMP * HID_DIM);
#pragma unroll
  for (int i = 0; i < 4; ++i) {
    float4 o;
    o.x = acc[i][0]; o.y = acc[i][1]; o.z = acc[i][2]; o.w = acc[i][3];
    *(float4*)&H[(long)(bm + row0 + i) * Nn + bn + col0] = o;
  }
}

// ---------------------------------------------------------------------------
// K3: Mup[s] = relu(sum_{p=0..3} Hp[p] + b1) @ W2[k-chunk s].
// A built inline from the 4 gemm1 partials (h never materialized).
// splitK=8 -> grid (4,16,8) = 512 blocks.
// ---------------------------------------------------------------------------
__global__ __launch_bounds__(256) void gemm2_kernel(
    const float* __restrict__ Hp, const float* __restrict__ b1,
    const float* __restrict__ B, float* __restrict__ Mup) {
  const int K = 512, Nn = 256;
  __shared__ float As[TBK][68];
  __shared__ float Bs[TBK][68];
  const int t = threadIdx.x;
  const int bn = blockIdx.x * 64;
  const int bm = blockIdx.y * 64;
  const int ks = blockIdx.z;          // 0..7, K-chunk of 64
  const long HS = (long)N_SAMP * HID_DIM;

  const int arow = t >> 2, acol = (t & 3) * 4;
  const int brow = t >> 4, bcol = (t & 15) * 4;
  const int row0 = (t >> 4) * 4, col0 = (t & 15) * 4;

  float acc[4][4] = {};
  const int k0 = ks * 64;

  long aidx = (long)(bm + arow) * K + k0 + acol;
  float4 a0 = *(const float4*)&Hp[aidx];
  float4 a1 = *(const float4*)&Hp[aidx + HS];
  float4 a2 = *(const float4*)&Hp[aidx + 2 * HS];
  float4 a3 = *(const float4*)&Hp[aidx + 3 * HS];
  float4 bb = *(const float4*)&b1[k0 + acol];
  float4 bv = *(const float4*)&B[(k0 + brow) * Nn + bn + bcol];

  for (int it = 0; it < 4; ++it) {
    float4 av;
    av.x = fmaxf(a0.x + a1.x + a2.x + a3.x + bb.x, 0.0f);
    av.y = fmaxf(a0.y + a1.y + a2.y + a3.y + bb.y, 0.0f);
    av.z = fmaxf(a0.z + a1.z + a2.z + a3.z + bb.z, 0.0f);
    av.w = fmaxf(a0.w + a1.w + a2.w + a3.w + bb.w, 0.0f);
    __syncthreads();
    As[acol + 0][arow] = av.x;
    As[acol + 1][arow] = av.y;
    As[acol + 2][arow] = av.z;
    As[acol + 3][arow] = av.w;
    *(float4*)&Bs[brow][bcol] = bv;
    __syncthreads();
    if (it < 3) {
      const int k1 = k0 + (it + 1) * TBK;
      aidx = (long)(bm + arow) * K + k1 + acol;
      a0 = *(const float4*)&Hp[aidx];
      a1 = *(const float4*)&Hp[aidx + HS];
      a2 = *(const float4*)&Hp[aidx + 2 * HS];
      a3 = *(const float4*)&Hp[aidx + 3 * HS];
      bb = *(const float4*)&b1[k1 + acol];
      bv = *(const float4*)&B[(k1 + brow) * Nn + bn + bcol];
    }
#pragma unroll
    for (int kk = 0; kk < TBK; ++kk) {
      float4 a = *(const float4*)&As[kk][row0];
      float4 b = *(const float4*)&Bs[kk][col0];
      acc[0][0] += a.x * b.x; acc[0][1] += a.x * b.y; acc[0][2] += a.x * b.z; acc[0][3] += a.x * b.w;
      acc[1][0] += a.y * b.x; acc[1][1] += a.y * b.y; acc[1][2] += a.y * b.z; acc[1][3] += a.y * b.w;
      acc[2][0] += a.z * b.x; acc[2][1] += a.z * b.y; acc[2][2] += a.z * b.z; acc[2][3] += a.z * b.w;
      acc[3][0] += a.w * b.x; acc[3][1] += a.w * b.y; acc[3][2] += a.w * b.z; acc[3][3] += a.w * b.w;
    }
  }

  float* M = Mup + (long)ks * (N_SAMP * YC_DIM);
#pragma unroll
  for (int i = 0; i < 4; ++i) {
    float4 o;
    o.x = acc[i][0]; o.y = acc[i][1]; o.z = acc[i][2]; o.w = acc[i][3];
    *(float4*)&M[(long)(bm + row0 + i) * Nn + bn + col0] = o;
  }
}

// ---------------------------------------------------------------------------
// K4: fold mu = sum Mup + b2; accumulate dot(mu,y), colsum_mu, colsum_y.
// R2: 64 -> 256 blocks (4 rows each); 64 blocks was 1 block per 4 CUs.
// ---------------------------------------------------------------------------
__global__ __launch_bounds__(256) void reduce_kernel(
    const float* __restrict__ Mup, const float* __restrict__ b2,
    const float* __restrict__ yv, float* __restrict__ colsum_mu,
    float* __restrict__ colsum_y, float* __restrict__ dot_out) {
  const int d = threadIdx.x;
  const int n0 = blockIdx.x * 4;
  const long MS = (long)N_SAMP * YC_DIM;
  const float bb = b2[d];
  float cm = 0.f, cy = 0.f, dp = 0.f;
#pragma unroll
  for (int r = 0; r < 4; ++r) {
    const long idx = (long)(n0 + r) * YC_DIM + d;
    float mu = bb;
#pragma unroll
    for (int s = 0; s < 8; ++s) mu += Mup[idx + s * MS];
    const float yy = yv[idx];
    dp += mu * yy;
    cm += mu;
    cy += yy;
  }
  atomicAdd(&colsum_mu[d], cm);
  atomicAdd(&colsum_y[d], cy);
#pragma unroll
  for (int off = 1; off < 64; off <<= 1) dp += __shfl_xor(dp, off);
  if ((d & 63) == 0) atomicAdd(dot_out, dp);
}

// ---------------------------------------------------------------------------
// K5: out = dot/N - (1/N^2) * sum_d colsum_y[d]*colsum_mu[d]
// ---------------------------------------------------------------------------
__global__ __launch_bounds__(256) void finalize_kernel(
    const float* __restrict__ colsum_mu, const float* __restrict__ colsum_y,
    const float* __restrict__ dot_in, float* __restrict__ out) {
  __shared__ float partial[4];
  const int t = threadIdx.x;
  float v = colsum_mu[t] * colsum_y[t];
#pragma unroll
  for (int off = 1; off < 64; off <<= 1) v += __shfl_xor(v, off);
  if ((t & 63) == 0) partial[t >> 6] = v;
  __syncthreads();
  if (t == 0) {
    float tot = partial[0] + partial[1] + partial[2] + partial[3];
    out[0] = dot_in[0] * (1.0f / 1024.0f) - tot * (1.0f / (1024.0f * 1024.0f));
  }
}

// ---------------------------------------------------------------------------
extern "C" void kernel_launch(void* const* d_in, const int* in_sizes, int n_in,
                              void* d_out, int out_size, void* d_ws, size_t ws_size,
                              hipStream_t stream) {
  const float* x  = (const float*)d_in[0];
  const float* y  = (const float*)d_in[1];
  const float* W1 = (const float*)d_in[2];
  const float* b1 = (const float*)d_in[3];
  const float* W2 = (const float*)d_in[4];
  const float* b2 = (const float*)d_in[5];
  float* out = (float*)d_out;

  char* ws = (char*)d_ws;
  float* x_vec = (float*)ws;                    // 2 MB
  float* y_vec = (float*)(ws + (2lu << 20));    // 1 MB
  float* Hp    = (float*)(ws + (4lu << 20));    // 4 x 2 MB = 8 MB
  float* Mup   = (float*)(ws + (12lu << 20));   // 8 x 1 MB = 8 MB
  float* accum = (float*)(ws + (20lu << 20));
  float* colsum_mu = accum;
  float* colsum_y  = accum + 256;
  float* dotp      = accum + 512;

  hipMemsetAsync(accum, 0, 513 * sizeof(float), stream);

  pool_kernel<<<24576, 256, 0, stream>>>(x, y, x_vec, y_vec);

  gemm1_kernel<<<dim3(8, 16, 4), 256, 0, stream>>>(x_vec, W1, Hp);

  gemm2_kernel<<<dim3(4, 16, 8), 256, 0, stream>>>(Hp, b1, W2, Mup);

  reduce_kernel<<<256, 256, 0, stream>>>(Mup, b2, y_vec, colsum_mu,
                                         colsum_y, dotp);

  finalize_kernel<<<1, 256, 0, stream>>>(colsum_mu, colsum_y, dotp, out);
}

// Round 3
// 261.276 us; speedup vs baseline: 1.0621x; 1.0621x over previous
//
#include <hip/hip_runtime.h>

#define N_SAMP 1024
#define XC_DIM 512
#define YC_DIM 256
#define HID_DIM 512

// ---------------------------------------------------------------------------
// K1: fused spatial pooling — TLP-structured (copy-bench shape).
// 2 loads/thread, 32 outputs/block, 24576 blocks; latency hidden by wave
// count. R2 showed pool dropped out of the top-5 (<76us) but TOTAL stayed
// 277us -> the session bottleneck is dispatch count, not this kernel.
// ---------------------------------------------------------------------------
__global__ __launch_bounds__(256) void pool_kernel(
    const float* __restrict__ x, const float* __restrict__ y,
    float* __restrict__ x_vec, float* __restrict__ y_vec) {
  __shared__ float s[16 * 33];  // [k][o] k=0..15, o=0..31 (pad 33)
  const int t = threadIdx.x;
  const long blk = blockIdx.x;
  const float4* src;
  float* dst;
  long obase;
  if (blk < 16384) {           // x: 524288 outputs / 32 = 16384 blocks
    src = (const float4*)x; dst = x_vec; obase = blk * 32;
  } else {                     // y: 262144 outputs / 32 = 8192 blocks
    src = (const float4*)y; dst = y_vec; obase = (blk - 16384) * 32;
  }
  const float4* p = src + obase * 16;  // 512 float4 per block

  float4 v0 = p[t];
  float4 v1 = p[t + 256];
  float h0 = (v0.x + v0.y) + (v0.z + v0.w);
  float h1 = (v1.x + v1.y) + (v1.z + v1.w);

  s[(t & 15) * 33 + (t >> 4)] = h0;
  s[(t & 15) * 33 + 16 + (t >> 4)] = h1;
  __syncthreads();

  const int o = t >> 3;        // 0..31
  const int r = t & 7;
  float dp = s[(2 * r) * 33 + o] + s[(2 * r + 1) * 33 + o];
#pragma unroll
  for (int off = 1; off < 8; off <<= 1) dp += __shfl_xor(dp, off);
  if (r == 0) dst[obase + o] = dp * (1.0f / 64.0f);
}

// ---------------------------------------------------------------------------
// K2: Hp[s] = x_vec @ W1[k-chunk s]. 64x64 tile, 4x4/thread, BK=16,
// splitK=4 (chunk 128 = 8 iters) -> grid (8,16,4) = 512 blocks = 2/CU.
// ---------------------------------------------------------------------------
#define TBK 16

__global__ __launch_bounds__(256) void gemm1_kernel(
    const float* __restrict__ A, const float* __restrict__ B,
    float* __restrict__ Hp) {
  const int K = 512, Nn = 512;
  __shared__ float As[TBK][68];
  __shared__ float Bs[TBK][68];
  const int t = threadIdx.x;
  const int bn = blockIdx.x * 64;
  const int bm = blockIdx.y * 64;
  const int ks = blockIdx.z;          // 0..3, K-chunk of 128

  const int arow = t >> 2, acol = (t & 3) * 4;
  const int brow = t >> 4, bcol = (t & 15) * 4;
  const int row0 = (t >> 4) * 4, col0 = (t & 15) * 4;

  float acc[4][4] = {};
  const int k0 = ks * 128;

  float4 av = *(const float4*)&A[(bm + arow) * K + k0 + acol];
  float4 bv = *(const float4*)&B[(k0 + brow) * Nn + bn + bcol];

  for (int it = 0; it < 8; ++it) {
    __syncthreads();
    As[acol + 0][arow] = av.x;
    As[acol + 1][arow] = av.y;
    As[acol + 2][arow] = av.z;
    As[acol + 3][arow] = av.w;
    *(float4*)&Bs[brow][bcol] = bv;
    __syncthreads();
    if (it < 7) {
      const int k1 = k0 + (it + 1) * TBK;
      av = *(const float4*)&A[(bm + arow) * K + k1 + acol];
      bv = *(const float4*)&B[(k1 + brow) * Nn + bn + bcol];
    }
#pragma unroll
    for (int kk = 0; kk < TBK; ++kk) {
      float4 a = *(const float4*)&As[kk][row0];
      float4 b = *(const float4*)&Bs[kk][col0];
      acc[0][0] += a.x * b.x; acc[0][1] += a.x * b.y; acc[0][2] += a.x * b.z; acc[0][3] += a.x * b.w;
      acc[1][0] += a.y * b.x; acc[1][1] += a.y * b.y; acc[1][2] += a.y * b.z; acc[1][3] += a.y * b.w;
      acc[2][0] += a.z * b.x; acc[2][1] += a.z * b.y; acc[2][2] += a.z * b.z; acc[2][3] += a.z * b.w;
      acc[3][0] += a.w * b.x; acc[3][1] += a.w * b.y; acc[3][2] += a.w * b.z; acc[3][3] += a.w * b.w;
    }
  }

  float* H = Hp + (long)ks * (N_SAMP * HID_DIM);
#pragma unroll
  for (int i = 0; i < 4; ++i) {
    float4 o;
    o.x = acc[i][0]; o.y = acc[i][1]; o.z = acc[i][2]; o.w = acc[i][3];
    *(float4*)&H[(long)(bm + row0 + i) * Nn + bn + col0] = o;
  }
}

// ---------------------------------------------------------------------------
// K3: fused gemm2 + reduction. Mup = relu(sum Hp + b1) @ W2 is never
// materialized: every reduction downstream (dot(mu,y), colsum_mu, colsum_y)
// is LINEAR in the splitK partials, so each block reduces its own acc tile:
//   dot_part[bid]           = sum_ij acc*y          (512 floats scratch)
//   cs_part[bm*8+ks][256]   = per-block colsum(acc) (128x256 scratch)
//   ycs_part[bm][256]       = colsum(y tile), ks==0 blocks only
// b2 terms applied analytically in finalize. No atomics -> no memset.
// Removes reduce_kernel dispatch + 16MB Mup traffic.
// ---------------------------------------------------------------------------
__global__ __launch_bounds__(256) void gemm2_kernel(
    const float* __restrict__ Hp, const float* __restrict__ b1,
    const float* __restrict__ B, const float* __restrict__ yv,
    float* __restrict__ cs_part, float* __restrict__ ycs_part,
    float* __restrict__ dot_part) {
  const int K = 512, Nn = 256;
  __shared__ float As[TBK][68];
  __shared__ float Bs[TBK][68];
  __shared__ float redd[4];
  const int t = threadIdx.x;
  const int bn = blockIdx.x * 64;
  const int bm = blockIdx.y * 64;
  const int ks = blockIdx.z;          // 0..7, K-chunk of 64
  const long HS = (long)N_SAMP * HID_DIM;

  const int arow = t >> 2, acol = (t & 3) * 4;
  const int brow = t >> 4, bcol = (t & 15) * 4;
  const int row0 = (t >> 4) * 4, col0 = (t & 15) * 4;

  float acc[4][4] = {};
  const int k0 = ks * 64;

  long aidx = (long)(bm + arow) * K + k0 + acol;
  float4 a0 = *(const float4*)&Hp[aidx];
  float4 a1 = *(const float4*)&Hp[aidx + HS];
  float4 a2 = *(const float4*)&Hp[aidx + 2 * HS];
  float4 a3 = *(const float4*)&Hp[aidx + 3 * HS];
  float4 bb = *(const float4*)&b1[k0 + acol];
  float4 bv = *(const float4*)&B[(k0 + brow) * Nn + bn + bcol];

  for (int it = 0; it < 4; ++it) {
    float4 av;
    av.x = fmaxf(a0.x + a1.x + a2.x + a3.x + bb.x, 0.0f);
    av.y = fmaxf(a0.y + a1.y + a2.y + a3.y + bb.y, 0.0f);
    av.z = fmaxf(a0.z + a1.z + a2.z + a3.z + bb.z, 0.0f);
    av.w = fmaxf(a0.w + a1.w + a2.w + a3.w + bb.w, 0.0f);
    __syncthreads();
    As[acol + 0][arow] = av.x;
    As[acol + 1][arow] = av.y;
    As[acol + 2][arow] = av.z;
    As[acol + 3][arow] = av.w;
    *(float4*)&Bs[brow][bcol] = bv;
    __syncthreads();
    if (it < 3) {
      const int k1 = k0 + (it + 1) * TBK;
      aidx = (long)(bm + arow) * K + k1 + acol;
      a0 = *(const float4*)&Hp[aidx];
      a1 = *(const float4*)&Hp[aidx + HS];
      a2 = *(const float4*)&Hp[aidx + 2 * HS];
      a3 = *(const float4*)&Hp[aidx + 3 * HS];
      bb = *(const float4*)&b1[k1 + acol];
      bv = *(const float4*)&B[(k1 + brow) * Nn + bn + bcol];
    }
#pragma unroll
    for (int kk = 0; kk < TBK; ++kk) {
      float4 a = *(const float4*)&As[kk][row0];
      float4 b = *(const float4*)&Bs[kk][col0];
      acc[0][0] += a.x * b.x; acc[0][1] += a.x * b.y; acc[0][2] += a.x * b.z; acc[0][3] += a.x * b.w;
      acc[1][0] += a.y * b.x; acc[1][1] += a.y * b.y; acc[1][2] += a.y * b.z; acc[1][3] += a.y * b.w;
      acc[2][0] += a.z * b.x; acc[2][1] += a.z * b.y; acc[2][2] += a.z * b.z; acc[2][3] += a.z * b.w;
      acc[3][0] += a.w * b.x; acc[3][1] += a.w * b.y; acc[3][2] += a.w * b.z; acc[3][3] += a.w * b.w;
    }
  }

  // ---- fused epilogue: dot(acc, y-tile), colsum(acc), colsum(y-tile) ----
  float dp = 0.f;
  float cmu0 = 0.f, cmu1 = 0.f, cmu2 = 0.f, cmu3 = 0.f;
  float cy0 = 0.f, cy1 = 0.f, cy2 = 0.f, cy3 = 0.f;
#pragma unroll
  for (int i = 0; i < 4; ++i) {
    const float4 yy = *(const float4*)&yv[(long)(bm + row0 + i) * Nn + bn + col0];
    dp += acc[i][0] * yy.x + acc[i][1] * yy.y + acc[i][2] * yy.z + acc[i][3] * yy.w;
    cmu0 += acc[i][0]; cmu1 += acc[i][1]; cmu2 += acc[i][2]; cmu3 += acc[i][3];
    cy0 += yy.x; cy1 += yy.y; cy2 += yy.z; cy3 += yy.w;
  }
#pragma unroll
  for (int off = 1; off < 64; off <<= 1) dp += __shfl_xor(dp, off);

  __syncthreads();  // all threads done reading As/Bs -> safe to reuse
  {
    float4 o; o.x = cmu0; o.y = cmu1; o.z = cmu2; o.w = cmu3;
    *(float4*)&As[t >> 4][col0] = o;
    float4 q; q.x = cy0; q.y = cy1; q.z = cy2; q.w = cy3;
    *(float4*)&Bs[t >> 4][col0] = q;
  }
  if ((t & 63) == 0) redd[t >> 6] = dp;
  __syncthreads();

  const int bid = blockIdx.x + 4 * blockIdx.y + 64 * blockIdx.z;
  if (t < 64) {
    float s = 0.f;
#pragma unroll
    for (int g = 0; g < 16; ++g) s += As[g][t];
    cs_part[(blockIdx.y * 8 + ks) * 256 + bn + t] = s;
  } else if (t < 128) {
    if (ks == 0) {
      const int c = t - 64;
      float s = 0.f;
#pragma unroll
      for (int g = 0; g < 16; ++g) s += Bs[g][c];
      ycs_part[blockIdx.y * 256 + bn + c] = s;
    }
  } else if (t == 128) {
    dot_part[bid] = redd[0] + redd[1] + redd[2] + redd[3];
  }
}

// ---------------------------------------------------------------------------
// K4: finalize. cm[d] = sum_p cs_part + N*b2[d]; cy[d] = sum_p ycs_part;
// dot = sum dot_part + sum_d b2[d]*cy[d];
// out = dot/N - (1/N^2)*sum_d cm[d]*cy[d].
// ---------------------------------------------------------------------------
__global__ __launch_bounds__(256) void finalize_kernel(
    const float* __restrict__ cs_part, const float* __restrict__ ycs_part,
    const float* __restrict__ dot_part, const float* __restrict__ b2,
    float* __restrict__ out) {
  __shared__ float red[3][4];
  const int t = threadIdx.x;  // = d
  const float b2d = b2[t];
  float cm = 1024.0f * b2d;
#pragma unroll 8
  for (int p = 0; p < 128; ++p) cm += cs_part[p * 256 + t];
  float cy = 0.f;
#pragma unroll
  for (int p = 0; p < 16; ++p) cy += ycs_part[p * 256 + t];
  float v1 = cm * cy;              // for sum_d cm*cy
  float v2 = b2d * cy;             // for b2 dot-term
  float v3 = dot_part[t] + dot_part[t + 256];
#pragma unroll
  for (int off = 1; off < 64; off <<= 1) {
    v1 += __shfl_xor(v1, off);
    v2 += __shfl_xor(v2, off);
    v3 += __shfl_xor(v3, off);
  }
  if ((t & 63) == 0) {
    red[0][t >> 6] = v1; red[1][t >> 6] = v2; red[2][t >> 6] = v3;
  }
  __syncthreads();
  if (t == 0) {
    float S1 = red[0][0] + red[0][1] + red[0][2] + red[0][3];
    float S2 = red[1][0] + red[1][1] + red[1][2] + red[1][3];
    float S0 = red[2][0] + red[2][1] + red[2][2] + red[2][3];
    float dot = S0 + S2;
    out[0] = dot * (1.0f / 1024.0f) - S1 * (1.0f / (1024.0f * 1024.0f));
  }
}

// ---------------------------------------------------------------------------
extern "C" void kernel_launch(void* const* d_in, const int* in_sizes, int n_in,
                              void* d_out, int out_size, void* d_ws, size_t ws_size,
                              hipStream_t stream) {
  const float* x  = (const float*)d_in[0];
  const float* y  = (const float*)d_in[1];
  const float* W1 = (const float*)d_in[2];
  const float* b1 = (const float*)d_in[3];
  const float* W2 = (const float*)d_in[4];
  const float* b2 = (const float*)d_in[5];
  float* out = (float*)d_out;

  char* ws = (char*)d_ws;
  float* x_vec = (float*)ws;                        // 2 MB
  float* y_vec = (float*)(ws + (2lu << 20));        // 1 MB
  float* Hp    = (float*)(ws + (4lu << 20));        // 4 x 2 MB = 8 MB
  float* cs_part  = (float*)(ws + (12lu << 20));            // 128*256*4 = 128 KB
  float* ycs_part = (float*)(ws + (12lu << 20) + (160lu << 10)); // 16 KB
  float* dot_part = (float*)(ws + (12lu << 20) + (192lu << 10)); // 2 KB

  pool_kernel<<<24576, 256, 0, stream>>>(x, y, x_vec, y_vec);

  gemm1_kernel<<<dim3(8, 16, 4), 256, 0, stream>>>(x_vec, W1, Hp);

  gemm2_kernel<<<dim3(4, 16, 8), 256, 0, stream>>>(Hp, b1, W2, y_vec,
                                                   cs_part, ycs_part, dot_part);

  finalize_kernel<<<1, 256, 0, stream>>>(cs_part, ycs_part, dot_part, b2, out);
}